// Round 4
// baseline (258058.936 us; speedup 1.0000x reference)
//
#include <hip/hip_runtime.h>
#include <cstddef>

namespace {
constexpr int kH = 16;   // hidden
constexpr int kL = 4;    // layers
constexpr int kF = 256;  // input features
constexpr int kA = 16;   // attention dim
constexpr int kG = 48;   // 3*H gates
}

// Pin a value into a VGPR at this point (opaque to the optimizer).
#define PIN(x) asm volatile("" : "+v"(x))

__device__ __forceinline__ float rl(float v, int lane) {
  return __int_as_float(__builtin_amdgcn_readlane(__float_as_int(v), lane));
}
// add value rotated by N within each 16-lane row (DPP row_ror)
template <int CTRL>
__device__ __forceinline__ float ror_add(float x) {
  int r = __builtin_amdgcn_update_dpp(0, __float_as_int(x), CTRL, 0xF, 0xF, false);
  return x + __int_as_float(r);
}
__device__ __forceinline__ float row_sum16(float x) {
  x = ror_add<0x128>(x);  // ror 8
  x = ror_add<0x124>(x);  // ror 4
  x = ror_add<0x122>(x);  // ror 2
  x = ror_add<0x121>(x);  // ror 1
  return x;
}
__device__ __forceinline__ float fast_rcp(float x) { return __builtin_amdgcn_rcpf(x); }
constexpr float kL2E = 1.4426950408889634f;
__device__ __forceinline__ float sigm(float x) {
  return fast_rcp(1.0f + __builtin_amdgcn_exp2f(-kL2E * x));
}
__device__ __forceinline__ float tanh_f(float x) {
  return 1.0f - 2.0f * fast_rcp(1.0f + __builtin_amdgcn_exp2f((2.0f * kL2E) * x));
}

// 4-way split dot of 16 broadcast scalars (SGPR) against per-lane weights.
#define DOT16(acc0, S, W)                         \
  {                                               \
    float _a0 = (acc0), _a1 = 0.f, _a2 = 0.f, _a3 = 0.f; \
    _Pragma("unroll")                             \
    for (int _k = 0; _k < kH; _k += 4) {          \
      _a0 = fmaf((S)[_k + 0], (W)[_k + 0], _a0);  \
      _a1 = fmaf((S)[_k + 1], (W)[_k + 1], _a1);  \
      _a2 = fmaf((S)[_k + 2], (W)[_k + 2], _a2);  \
      _a3 = fmaf((S)[_k + 3], (W)[_k + 3], _a3);  \
    }                                             \
    acc0 = (_a0 + _a1) + (_a2 + _a3);             \
  }

// ---------------- Kernel A: gi0[t][g] = bih0[g] + sum_f batch[t][f]*Wih0[g][f]
__global__ __launch_bounds__(256) void gi0_kernel(
    const float* __restrict__ batch, const float* __restrict__ Wih0,
    const float* __restrict__ bih0, float* __restrict__ gi0, int T) {
  __shared__ __align__(16) float w[kG * kF];
  __shared__ float bsh[kG];
  for (int i = threadIdx.x; i < kG * kF; i += blockDim.x) w[i] = Wih0[i];
  if (threadIdx.x < kG) bsh[threadIdx.x] = bih0[threadIdx.x];
  __syncthreads();
  int t = blockIdx.x * blockDim.x + threadIdx.x;
  if (t >= T) return;
  float acc[kG];
#pragma unroll
  for (int gg = 0; gg < kG; ++gg) acc[gg] = bsh[gg];
  const float* brow = batch + (size_t)t * kF;
  for (int f = 0; f < kF; f += 4) {
    const float4 b4 = *reinterpret_cast<const float4*>(brow + f);
#pragma unroll
    for (int gg = 0; gg < kG; ++gg) {
      const float4 w4 = *reinterpret_cast<const float4*>(&w[gg * kF + f]);
      acc[gg] = fmaf(b4.x, w4.x, acc[gg]);
      acc[gg] = fmaf(b4.y, w4.y, acc[gg]);
      acc[gg] = fmaf(b4.z, w4.z, acc[gg]);
      acc[gg] = fmaf(b4.w, w4.w, acc[gg]);
    }
  }
  float* orow = gi0 + (size_t)t * kG;
#pragma unroll
  for (int gg = 0; gg < kG; gg += 4) {
    *reinterpret_cast<float4*>(orow + gg) =
        make_float4(acc[gg], acc[gg + 1], acc[gg + 2], acc[gg + 3]);
  }
}

// ---------------- Kernel B: sequential recurrence, one wave, ALL-LOCAL gates.
// Every lane owns component a = lane&15 and computes r,z,n for it locally
// (4 redundant copies across the 4 groups). grp = lane>>4 is the attention
// head. State hs: lane 16*l+a holds h[l][a]. No intra-layer LDS crossings.
__global__ __launch_bounds__(64)
__attribute__((amdgpu_waves_per_eu(1, 1)))
void seq_kernel(
    const float* __restrict__ Whh0, const float* __restrict__ bhh0,
    const float* __restrict__ Wih, const float* __restrict__ Whh,
    const float* __restrict__ bih, const float* __restrict__ bhh,
    const float* __restrict__ aW, const float* __restrict__ ab,
    const float* __restrict__ av, const float* __restrict__ avb,
    const float* __restrict__ gi0, float* __restrict__ topout, int T) {
  const int lane = threadIdx.x & 63;
  const int grp = lane >> 4;
  const int a = lane & 15;

  // --- per-lane weight rows: component a's r,z,n rows for every layer ---
  float wr[kL][kH], wz[kL][kH], wn[kL][kH];   // hidden-hidden
  float ur[3][kH], uz[3][kH], un[3][kH];      // input-hidden (layers 1..3)
  float bhr[kL], bhz[kL], bhn[kL];
  float bir[3], biz[3], bin[3];
#pragma unroll
  for (int l = 0; l < kL; ++l) {
    const float* base = (l == 0) ? Whh0 : (Whh + (size_t)(l - 1) * kG * kH);
    const float* bb   = (l == 0) ? bhh0 : (bhh + (size_t)(l - 1) * kG);
#pragma unroll
    for (int k = 0; k < kH; ++k) {
      wr[l][k] = base[(0  + a) * kH + k];
      wz[l][k] = base[(16 + a) * kH + k];
      wn[l][k] = base[(32 + a) * kH + k];
    }
    bhr[l] = bb[0 + a]; bhz[l] = bb[16 + a]; bhn[l] = bb[32 + a];
  }
#pragma unroll
  for (int l = 0; l < 3; ++l) {
    const float* base = Wih + (size_t)l * kG * kH;
#pragma unroll
    for (int k = 0; k < kH; ++k) {
      ur[l][k] = base[(0  + a) * kH + k];
      uz[l][k] = base[(16 + a) * kH + k];
      un[l][k] = base[(32 + a) * kH + k];
    }
    bir[l] = bih[l * kG + 0 + a];
    biz[l] = bih[l * kG + 16 + a];
    bin[l] = bih[l * kG + 32 + a];
  }
  // attention params: head grp, unit a
  float aWr[kH];
#pragma unroll
  for (int k = 0; k < kH; ++k) aWr[k] = aW[(grp * kH + k) * kA + a];
  float abr = ab[grp * kA + a];
  float avr = av[grp * kA + a];
  float avbr = avb[grp];

  // pin all loop-invariant values into VGPRs
#pragma unroll
  for (int l = 0; l < kL; ++l) {
#pragma unroll
    for (int k = 0; k < kH; ++k) { PIN(wr[l][k]); PIN(wz[l][k]); PIN(wn[l][k]); }
    PIN(bhr[l]); PIN(bhz[l]); PIN(bhn[l]);
  }
#pragma unroll
  for (int l = 0; l < 3; ++l) {
#pragma unroll
    for (int k = 0; k < kH; ++k) { PIN(ur[l][k]); PIN(uz[l][k]); PIN(un[l][k]); }
    PIN(bir[l]); PIN(biz[l]); PIN(bin[l]);
  }
#pragma unroll
  for (int k = 0; k < kH; ++k) PIN(aWr[k]);
  PIN(abr); PIN(avr); PIN(avbr);

  float hs = 0.0f;
  // gi0 prefetch: three per-lane streams (r,z,n rows), depth 3
  const float* pr = gi0 + 0 + a;
  const float* pz = gi0 + 16 + a;
  const float* pn = gi0 + 32 + a;
  float r0 = pr[0], r1 = pr[kG], r2 = pr[2 * kG];
  float z0 = pz[0], z1 = pz[kG], z2 = pz[2 * kG];
  float n0 = pn[0], n1 = pn[kG], n2 = pn[2 * kG];

  for (int t = 0; t < T; ++t) {
    const float grc = r0, gzc = z0, gnc = n0;
    r0 = r1; r1 = r2; z0 = z1; z1 = z2; n0 = n1; n1 = n2;
    {
      int tn = t + 3;
      tn = tn < T ? tn : T - 1;
      const size_t off = (size_t)tn * kG;
      r2 = pr[off]; z2 = pz[off]; n2 = pn[off];
    }

    // old state per lane: hold[l] = h_prev[l][a] (bpermute, off critical path)
    const float hold0 = __shfl(hs, a, 64);
    const float hold1 = __shfl(hs, 16 + a, 64);
    const float hold2 = __shfl(hs, 32 + a, 64);
    const float hold3 = __shfl(hs, 48 + a, 64);

    float hn[kL];       // GRU outputs, identical in all 4 groups
    float sc[kL];       // attention scores (uniform per row)
    float xs[kL][kH];   // broadcast scalars of x_l

#pragma unroll
    for (int l = 0; l < kL; ++l) {
      // broadcast prev state of this layer
      float hb[kH];
#pragma unroll
      for (int k = 0; k < kH; ++k) hb[k] = rl(hs, l * kH + k);
      // hidden-hidden gates
      float ghr = bhr[l]; DOT16(ghr, hb, wr[l]);
      float ghz = bhz[l]; DOT16(ghz, hb, wz[l]);
      float ghn = bhn[l]; DOT16(ghn, hb, wn[l]);
      // input-hidden gates (layer 0 precomputed)
      float gir, giz, gin;
      if (l == 0) {
        gir = grc; giz = gzc; gin = gnc;
      } else {
        gir = bir[l - 1]; DOT16(gir, xs[l - 1], ur[l - 1]);
        giz = biz[l - 1]; DOT16(giz, xs[l - 1], uz[l - 1]);
        gin = bin[l - 1]; DOT16(gin, xs[l - 1], un[l - 1]);
      }
      const float rg = sigm(gir + ghr);
      const float zg = sigm(giz + ghz);
      const float nt = tanh_f(fmaf(rg, ghn, gin));
      const float hold = (l == 0) ? hold0 : (l == 1) ? hold1
                       : (l == 2) ? hold2 : hold3;
      const float hnew = fmaf(zg, hold - nt, nt);
      hn[l] = hnew;
#pragma unroll
      for (int k = 0; k < kH; ++k) xs[l][k] = rl(hnew, k);

      // attention score for j = l (head grp): d = tanh(aW.x_l + ab), s = v.d + vb
      {
        float d = abr; DOT16(d, xs[l], aWr);
        d = tanh_f(d);
        sc[l] = row_sum16(d * avr) + avbr;
      }
    }

    // masked softmax over j >= grp (uniform within each row)
    const float s0 = (grp == 0) ? sc[0] : -1e30f;
    const float s1 = (grp <= 1) ? sc[1] : -1e30f;
    const float s2 = (grp <= 2) ? sc[2] : -1e30f;
    const float s3 = sc[3];
    const float m = fmaxf(fmaxf(s0, s1), fmaxf(s2, s3));
    const float e0 = __builtin_amdgcn_exp2f((s0 - m) * kL2E);
    const float e1 = __builtin_amdgcn_exp2f((s1 - m) * kL2E);
    const float e2 = __builtin_amdgcn_exp2f((s2 - m) * kL2E);
    const float e3 = __builtin_amdgcn_exp2f((s3 - m) * kL2E);
    const float rden = fast_rcp((e0 + e1) + (e2 + e3));
    // mixing is fully lane-local: hn[j] == x_j[a] in every lane
    float num = e0 * hn[0];
    num = fmaf(e1, hn[1], num);
    num = fmaf(e2, hn[2], num);
    num = fmaf(e3, hn[3], num);
    hs = num * rden;

    if (lane >= 48) topout[(size_t)t * kH + a] = hs;  // head 3 output
  }
}

// ---------------- Kernel C: out[t] = fc2( relu( fc1( top[t] ) ) )
__global__ __launch_bounds__(256) void head_kernel(
    const float* __restrict__ top, const float* __restrict__ fc1W,
    const float* __restrict__ fc1b, const float* __restrict__ fc2W,
    const float* __restrict__ fc2b, float* __restrict__ out, int T) {
  __shared__ __align__(16) float w1[32 * kH];
  __shared__ float b1[32], w2[32];
  for (int i = threadIdx.x; i < 32 * kH; i += blockDim.x) w1[i] = fc1W[i];
  if (threadIdx.x < 32) {
    b1[threadIdx.x] = fc1b[threadIdx.x];
    w2[threadIdx.x] = fc2W[threadIdx.x];
  }
  __syncthreads();
  int t = blockIdx.x * blockDim.x + threadIdx.x;
  if (t >= T) return;
  const float* hrow = top + (size_t)t * kH;
  float hv[kH];
#pragma unroll
  for (int k = 0; k < kH; k += 4) {
    const float4 h4 = *reinterpret_cast<const float4*>(hrow + k);
    hv[k] = h4.x; hv[k + 1] = h4.y; hv[k + 2] = h4.z; hv[k + 3] = h4.w;
  }
  float o = fc2b[0];
#pragma unroll
  for (int mth = 0; mth < 32; ++mth) {
    float a = b1[mth];
#pragma unroll
    for (int k = 0; k < kH; ++k) a = fmaf(hv[k], w1[mth * kH + k], a);
    a = fmaxf(a, 0.0f);
    o = fmaf(a, w2[mth], o);
  }
  out[t] = o;
}

extern "C" void kernel_launch(void* const* d_in, const int* in_sizes, int n_in,
                              void* d_out, int out_size, void* d_ws, size_t ws_size,
                              hipStream_t stream) {
  const float* batch = (const float*)d_in[0];
  const float* Wih0  = (const float*)d_in[1];
  const float* Whh0  = (const float*)d_in[2];
  const float* bih0  = (const float*)d_in[3];
  const float* bhh0  = (const float*)d_in[4];
  const float* Wih   = (const float*)d_in[5];
  const float* Whh   = (const float*)d_in[6];
  const float* bih   = (const float*)d_in[7];
  const float* bhh   = (const float*)d_in[8];
  const float* aW    = (const float*)d_in[9];
  const float* ab    = (const float*)d_in[10];
  const float* av    = (const float*)d_in[11];
  const float* avb   = (const float*)d_in[12];
  const float* fc1W  = (const float*)d_in[13];
  const float* fc1b  = (const float*)d_in[14];
  const float* fc2W  = (const float*)d_in[15];
  const float* fc2b  = (const float*)d_in[16];
  float* out = (float*)d_out;

  const int T = in_sizes[0] / kF;  // 131072

  // workspace layout: gi0 [T*48 f32] | top [T*16 f32]
  float* gi0 = (float*)d_ws;
  float* top = gi0 + (size_t)T * kG;

  const int blocks = (T + 255) / 256;
  gi0_kernel<<<blocks, 256, 0, stream>>>(batch, Wih0, bih0, gi0, T);
  seq_kernel<<<1, 64, 0, stream>>>(Whh0, bhh0, Wih, Whh, bih, bhh,
                                   aW, ab, av, avb, gi0, top, T);
  head_kernel<<<blocks, 256, 0, stream>>>(top, fc1W, fc1b, fc2W, fc2b, out, T);
}

// Round 5
// 168441.040 us; speedup vs baseline: 1.5320x; 1.5320x over previous
//
#include <hip/hip_runtime.h>
#include <cstddef>

namespace {
constexpr int kH = 16;   // hidden
constexpr int kL = 4;    // layers
constexpr int kF = 256;  // input features
constexpr int kA = 16;   // attention dim
constexpr int kG = 48;   // 3*H gates
}

// Pin a value into a VGPR at this point (opaque to the optimizer).
#define PIN(x) asm volatile("" : "+v"(x))

__device__ __forceinline__ float rl(float v, int lane) {
  return __int_as_float(__builtin_amdgcn_readlane(__float_as_int(v), lane));
}
// own + partner(lane^32) via v_permlane32_swap_b32. Passing the same value in
// both operands makes the result independent of which operand-half the HW
// swaps: {a',b'} = {{lo,lo^},{hi^,hi}} in some order; a'+b' = cross+own both ways.
__device__ __forceinline__ float swap_sum(float x) {
  float p = x, q = x;
  asm("v_permlane32_swap_b32 %0, %1" : "+v"(p), "+v"(q));
  return p + q;
}
// add value rotated by N within each 16-lane row (DPP row_ror)
template <int CTRL>
__device__ __forceinline__ float ror_add(float x) {
  int r = __builtin_amdgcn_update_dpp(0, __float_as_int(x), CTRL, 0xF, 0xF, false);
  return x + __int_as_float(r);
}
__device__ __forceinline__ float row_sum16(float x) {
  x = ror_add<0x128>(x);  // ror 8
  x = ror_add<0x124>(x);  // ror 4
  x = ror_add<0x122>(x);  // ror 2
  x = ror_add<0x121>(x);  // ror 1
  return x;
}
__device__ __forceinline__ float fast_rcp(float x) { return __builtin_amdgcn_rcpf(x); }
constexpr float kL2E = 1.4426950408889634f;
__device__ __forceinline__ float sigm(float x) {
  return fast_rcp(1.0f + __builtin_amdgcn_exp2f(-kL2E * x));
}
__device__ __forceinline__ float tanh_f(float x) {
  return 1.0f - 2.0f * fast_rcp(1.0f + __builtin_amdgcn_exp2f((2.0f * kL2E) * x));
}

// 4-way split dot of 16 broadcast scalars against per-lane weights.
#define DOT16(acc0, S, W)                         \
  {                                               \
    float _a0 = (acc0), _a1 = 0.f, _a2 = 0.f, _a3 = 0.f; \
    _Pragma("unroll")                             \
    for (int _k = 0; _k < kH; _k += 4) {          \
      _a0 = fmaf((S)[_k + 0], (W)[_k + 0], _a0);  \
      _a1 = fmaf((S)[_k + 1], (W)[_k + 1], _a1);  \
      _a2 = fmaf((S)[_k + 2], (W)[_k + 2], _a2);  \
      _a3 = fmaf((S)[_k + 3], (W)[_k + 3], _a3);  \
    }                                             \
    acc0 = (_a0 + _a1) + (_a2 + _a3);             \
  }

// ---------------- Kernel A: gi0[t][g] = bih0[g] + sum_f batch[t][f]*Wih0[g][f]
__global__ __launch_bounds__(256) void gi0_kernel(
    const float* __restrict__ batch, const float* __restrict__ Wih0,
    const float* __restrict__ bih0, float* __restrict__ gi0, int T) {
  __shared__ __align__(16) float w[kG * kF];
  __shared__ float bsh[kG];
  for (int i = threadIdx.x; i < kG * kF; i += blockDim.x) w[i] = Wih0[i];
  if (threadIdx.x < kG) bsh[threadIdx.x] = bih0[threadIdx.x];
  __syncthreads();
  int t = blockIdx.x * blockDim.x + threadIdx.x;
  if (t >= T) return;
  float acc[kG];
#pragma unroll
  for (int gg = 0; gg < kG; ++gg) acc[gg] = bsh[gg];
  const float* brow = batch + (size_t)t * kF;
  for (int f = 0; f < kF; f += 4) {
    const float4 b4 = *reinterpret_cast<const float4*>(brow + f);
#pragma unroll
    for (int gg = 0; gg < kG; ++gg) {
      const float4 w4 = *reinterpret_cast<const float4*>(&w[gg * kF + f]);
      acc[gg] = fmaf(b4.x, w4.x, acc[gg]);
      acc[gg] = fmaf(b4.y, w4.y, acc[gg]);
      acc[gg] = fmaf(b4.z, w4.z, acc[gg]);
      acc[gg] = fmaf(b4.w, w4.w, acc[gg]);
    }
  }
  float* orow = gi0 + (size_t)t * kG;
#pragma unroll
  for (int gg = 0; gg < kG; gg += 4) {
    *reinterpret_cast<float4*>(orow + gg) =
        make_float4(acc[gg], acc[gg + 1], acc[gg + 2], acc[gg + 3]);
  }
}

// ---------------- Kernel B: sequential recurrence, one wave.
// Lanes 0-31: component a = lane&15, gates r & n (weights wr, wn, ur).
// Lanes 32-63: component a, gate z (weights wz, uz) + the un rows for gin.
// Cross-half z/gin delivery via v_permlane32_swap (VALU). Attention head =
// lane>>4 as before. State hs: lane 16*l+a holds h[l][a].
__global__ __launch_bounds__(64)
__attribute__((amdgpu_waves_per_eu(1, 1)))
void seq_kernel(
    const float* __restrict__ Whh0, const float* __restrict__ bhh0,
    const float* __restrict__ Wih, const float* __restrict__ Whh,
    const float* __restrict__ bih, const float* __restrict__ bhh,
    const float* __restrict__ aW, const float* __restrict__ ab,
    const float* __restrict__ av, const float* __restrict__ avb,
    const float* __restrict__ gi0, float* __restrict__ topout, int T) {
  const int lane = threadIdx.x & 63;
  const int grp = lane >> 4;
  const int a = lane & 15;
  const bool zh = lane >= 32;            // z-half
  const int rowA = zh ? 16 + a : a;      // r-row (low half) / z-row (high half)
  const int rowB = 32 + a;               // n-row

  // --- per-lane weights ---
  // W1[l] = Whh_l[rowA]  (low: wr, high: wz)
  // W2[l] = low: Whh_l[rowB] (wn, for hb-dot) ; high, l>=1: Wih_l[rowB] (un, for xs-dot)
  // U1[l-1] = Wih_l[rowA] (low: ur, high: uz)
  float W1[kL][kH], W2[kL][kH], U1[3][kH];
#pragma unroll
  for (int k = 0; k < kH; ++k) {
    W1[0][k] = Whh0[rowA * kH + k];
    W2[0][k] = Whh0[rowB * kH + k];
  }
#pragma unroll
  for (int l = 1; l < kL; ++l) {
    const float* wh = Whh + (size_t)(l - 1) * kG * kH;
    const float* wi = Wih + (size_t)(l - 1) * kG * kH;
#pragma unroll
    for (int k = 0; k < kH; ++k) {
      W1[l][k] = wh[rowA * kH + k];
      W2[l][k] = zh ? wi[rowB * kH + k] : wh[rowB * kH + k];
      U1[l - 1][k] = wi[rowA * kH + k];
    }
  }
  float bAh[kL], bBh[kL], bAx[3], bBx[3];
  bAh[0] = bhh0[rowA];
  bBh[0] = bhh0[rowB];
#pragma unroll
  for (int l = 1; l < kL; ++l) {
    bAh[l] = bhh[(l - 1) * kG + rowA];
    bBh[l] = bhh[(l - 1) * kG + rowB];
    bAx[l - 1] = bih[(l - 1) * kG + rowA];
    bBx[l - 1] = bih[(l - 1) * kG + rowB];
  }
  // attention params: head grp, unit a
  float aWr[kH];
#pragma unroll
  for (int k = 0; k < kH; ++k) aWr[k] = aW[(grp * kH + k) * kA + a];
  float abr = ab[grp * kA + a];
  float avr = av[grp * kA + a];
  float avbr = avb[grp];

  // pin all loop-invariants into VGPRs
#pragma unroll
  for (int l = 0; l < kL; ++l) {
#pragma unroll
    for (int k = 0; k < kH; ++k) { PIN(W1[l][k]); PIN(W2[l][k]); }
    PIN(bAh[l]); PIN(bBh[l]);
  }
#pragma unroll
  for (int l = 0; l < 3; ++l) {
#pragma unroll
    for (int k = 0; k < kH; ++k) PIN(U1[l][k]);
    PIN(bAx[l]); PIN(bBx[l]);
  }
#pragma unroll
  for (int k = 0; k < kH; ++k) PIN(aWr[k]);
  PIN(abr); PIN(avr); PIN(avbr);

  float hs = 0.0f;
  float hold0 = 0.f, hold1 = 0.f, hold2 = 0.f, hold3 = 0.f;
  // gi0 prefetch streams, depth 3
  const float* pA = gi0 + rowA;
  const float* pB = gi0 + rowB;
  float gA0 = pA[0], gA1 = pA[kG], gA2 = pA[2 * kG];
  float gB0 = pB[0], gB1 = pB[kG], gB2 = pB[2 * kG];

  for (int t = 0; t < T; ++t) {
    const float sA = gA0, sB = gB0;
    gA0 = gA1; gA1 = gA2; gB0 = gB1; gB1 = gB2;
    {
      int tn = t + 3;
      tn = tn < T ? tn : T - 1;
      const size_t off = (size_t)tn * kG;
      gA2 = pA[off]; gB2 = pB[off];
    }

    float xs[kL][kH];  // broadcast copies of layer outputs (SGPRs)
    float sc[kL];      // attention scores (uniform per row)
    float xg[kL];      // per-lane x_j[a] for the mix (bpermute, hidden)

#pragma unroll
    for (int l = 0; l < kL; ++l) {
      float hb[kH];
#pragma unroll
      for (int k = 0; k < kH; ++k) hb[k] = rl(hs, l * kH + k);
      float ghA = bAh[l]; DOT16(ghA, hb, W1[l]);   // low: ghr, high: ghz
      float ghn = bBh[l]; DOT16(ghn, hb, W2[l]);   // low: ghn, high: junk
      float giA, gin;
      if (l == 0) {
        giA = sA;                                   // low: gir0, high: giz0
        gin = sB;                                   // gin0 (all lanes)
      } else {
        giA = bAx[l - 1]; DOT16(giA, xs[l - 1], U1[l - 1]);  // low: gir, high: giz
        float gp = bBx[l - 1]; DOT16(gp, xs[l - 1], W2[l]);  // high: gin, low: junk
        gin = swap_sum(zh ? gp : 0.0f);             // gin delivered to all lanes
      }
      const float gAte = sigm(giA + ghA);           // low: r, high: z
      const float z_ = swap_sum(zh ? gAte : 0.0f);  // z delivered to all lanes
      const float nt = tanh_f(fmaf(gAte, ghn, gin));  // valid low half (r local)
      const float hold = (l == 0) ? hold0 : (l == 1) ? hold1
                       : (l == 2) ? hold2 : hold3;
      const float hnew = fmaf(z_, hold - nt, nt);   // valid in row0 lanes
#pragma unroll
      for (int k = 0; k < kH; ++k) xs[l][k] = rl(hnew, k);
      // attention score for j = l (each row its own head), from xs scalars
      float d = abr; DOT16(d, xs[l], aWr);
      d = tanh_f(d);
      sc[l] = row_sum16(d * avr) + avbr;
      // per-lane copy of x_l[a] for the mix (bpermute latency hidden by later layers)
      xg[l] = __shfl(hnew, a, 64);
    }

    // masked softmax over j >= grp (uniform within each row)
    const float s0 = (grp == 0) ? sc[0] : -1e30f;
    const float s1 = (grp <= 1) ? sc[1] : -1e30f;
    const float s2 = (grp <= 2) ? sc[2] : -1e30f;
    const float s3 = sc[3];
    const float m = fmaxf(fmaxf(s0, s1), fmaxf(s2, s3));
    const float e0 = __builtin_amdgcn_exp2f((s0 - m) * kL2E);
    const float e1 = __builtin_amdgcn_exp2f((s1 - m) * kL2E);
    const float e2 = __builtin_amdgcn_exp2f((s2 - m) * kL2E);
    const float e3 = __builtin_amdgcn_exp2f((s3 - m) * kL2E);
    const float rden = fast_rcp((e0 + e1) + (e2 + e3));
    float num = e0 * xg[0];
    num = fmaf(e1, xg[1], num);
    num = fmaf(e2, xg[2], num);
    num = fmaf(e3, xg[3], num);
    hs = num * rden;

    // hold gathers for next step (latency hidden across the iteration boundary)
    hold0 = __shfl(hs, a, 64);
    hold1 = __shfl(hs, 16 + a, 64);
    hold2 = __shfl(hs, 32 + a, 64);
    hold3 = __shfl(hs, 48 + a, 64);

    if (lane >= 48) topout[(size_t)t * kH + a] = hs;  // head-3 output
  }
}

// ---------------- Kernel C: out[t] = fc2( relu( fc1( top[t] ) ) )
__global__ __launch_bounds__(256) void head_kernel(
    const float* __restrict__ top, const float* __restrict__ fc1W,
    const float* __restrict__ fc1b, const float* __restrict__ fc2W,
    const float* __restrict__ fc2b, float* __restrict__ out, int T) {
  __shared__ __align__(16) float w1[32 * kH];
  __shared__ float b1[32], w2[32];
  for (int i = threadIdx.x; i < 32 * kH; i += blockDim.x) w1[i] = fc1W[i];
  if (threadIdx.x < 32) {
    b1[threadIdx.x] = fc1b[threadIdx.x];
    w2[threadIdx.x] = fc2W[threadIdx.x];
  }
  __syncthreads();
  int t = blockIdx.x * blockDim.x + threadIdx.x;
  if (t >= T) return;
  const float* hrow = top + (size_t)t * kH;
  float hv[kH];
#pragma unroll
  for (int k = 0; k < kH; k += 4) {
    const float4 h4 = *reinterpret_cast<const float4*>(hrow + k);
    hv[k] = h4.x; hv[k + 1] = h4.y; hv[k + 2] = h4.z; hv[k + 3] = h4.w;
  }
  float o = fc2b[0];
#pragma unroll
  for (int mth = 0; mth < 32; ++mth) {
    float acc = b1[mth];
#pragma unroll
    for (int k = 0; k < kH; ++k) acc = fmaf(hv[k], w1[mth * kH + k], acc);
    acc = fmaxf(acc, 0.0f);
    o = fmaf(acc, w2[mth], o);
  }
  out[t] = o;
}

extern "C" void kernel_launch(void* const* d_in, const int* in_sizes, int n_in,
                              void* d_out, int out_size, void* d_ws, size_t ws_size,
                              hipStream_t stream) {
  const float* batch = (const float*)d_in[0];
  const float* Wih0  = (const float*)d_in[1];
  const float* Whh0  = (const float*)d_in[2];
  const float* bih0  = (const float*)d_in[3];
  const float* bhh0  = (const float*)d_in[4];
  const float* Wih   = (const float*)d_in[5];
  const float* Whh   = (const float*)d_in[6];
  const float* bih   = (const float*)d_in[7];
  const float* bhh   = (const float*)d_in[8];
  const float* aW    = (const float*)d_in[9];
  const float* ab    = (const float*)d_in[10];
  const float* av    = (const float*)d_in[11];
  const float* avb   = (const float*)d_in[12];
  const float* fc1W  = (const float*)d_in[13];
  const float* fc1b  = (const float*)d_in[14];
  const float* fc2W  = (const float*)d_in[15];
  const float* fc2b  = (const float*)d_in[16];
  float* out = (float*)d_out;

  const int T = in_sizes[0] / kF;  // 131072

  // workspace layout: gi0 [T*48 f32] | top [T*16 f32]
  float* gi0 = (float*)d_ws;
  float* top = gi0 + (size_t)T * kG;

  const int blocks = (T + 255) / 256;
  gi0_kernel<<<blocks, 256, 0, stream>>>(batch, Wih0, bih0, gi0, T);
  seq_kernel<<<1, 64, 0, stream>>>(Whh0, bhh0, Wih, Whh, bih, bhh,
                                   aW, ab, av, avb, gi0, top, T);
  head_kernel<<<blocks, 256, 0, stream>>>(top, fc1W, fc1b, fc2W, fc2b, out, T);
}

// Round 7
// 159932.996 us; speedup vs baseline: 1.6135x; 1.0532x over previous
//
#include <hip/hip_runtime.h>
#include <cstddef>

namespace {
constexpr int kH = 16;   // hidden
constexpr int kL = 4;    // layers
constexpr int kF = 256;  // input features
constexpr int kA = 16;   // attention dim
constexpr int kG = 48;   // 3*H gates
}

// Pin a value into a VGPR at this point (opaque to the optimizer).
#define PIN(x) asm volatile("" : "+v"(x))

__device__ __forceinline__ float rl(float v, int lane) {
  return __int_as_float(__builtin_amdgcn_readlane(__float_as_int(v), lane));
}

// x[i] + x[i^32] / x[i] + x[i^16], via the gfx950 permlane-swap builtins.
// Feeding the same value to both operands makes res0+res1 equal own+partner
// under ANY complementary-half-swap operand convention. The builtins (unlike
// raw asm with two "+v" ties to one SSA value) guarantee correct two-output
// register handling — the suspected R6 failure mode.
#if defined(__has_builtin)
#if __has_builtin(__builtin_amdgcn_permlane16_swap) && __has_builtin(__builtin_amdgcn_permlane32_swap)
#define HAVE_PLSWAP 1
#endif
#endif

#ifdef HAVE_PLSWAP
__device__ __forceinline__ float swap_sum32(float x) {
  auto r = __builtin_amdgcn_permlane32_swap(__float_as_uint(x), __float_as_uint(x), false, false);
  return __uint_as_float(r[0]) + __uint_as_float(r[1]);
}
__device__ __forceinline__ float swap_sum16(float x) {
  auto r = __builtin_amdgcn_permlane16_swap(__float_as_uint(x), __float_as_uint(x), false, false);
  return __uint_as_float(r[0]) + __uint_as_float(r[1]);
}
#else
__device__ __forceinline__ float swap_sum32(float x) {
  return x + __shfl(x, (int)(threadIdx.x & 63) ^ 32, 64);
}
__device__ __forceinline__ float swap_sum16(float x) {
  return x + __shfl(x, (int)(threadIdx.x & 63) ^ 16, 64);
}
#endif

// add value rotated by N within each 16-lane row (DPP row_ror)
template <int CTRL>
__device__ __forceinline__ float ror_add(float x) {
  int r = __builtin_amdgcn_update_dpp(0, __float_as_int(x), CTRL, 0xF, 0xF, false);
  return x + __int_as_float(r);
}
__device__ __forceinline__ float row_sum16(float x) {
  x = ror_add<0x128>(x);  // ror 8
  x = ror_add<0x124>(x);  // ror 4
  x = ror_add<0x122>(x);  // ror 2
  x = ror_add<0x121>(x);  // ror 1
  return x;
}
__device__ __forceinline__ float fast_rcp(float x) { return __builtin_amdgcn_rcpf(x); }
constexpr float kL2E = 1.4426950408889634f;
__device__ __forceinline__ float sigm(float x) {
  return fast_rcp(1.0f + __builtin_amdgcn_exp2f(-kL2E * x));
}
__device__ __forceinline__ float tanh_f(float x) {
  return 1.0f - 2.0f * fast_rcp(1.0f + __builtin_amdgcn_exp2f((2.0f * kL2E) * x));
}

// 4-way split dot of 16 broadcast scalars against per-lane weights.
#define DOT16(acc0, S, W)                         \
  {                                               \
    float _a0 = (acc0), _a1 = 0.f, _a2 = 0.f, _a3 = 0.f; \
    _Pragma("unroll")                             \
    for (int _k = 0; _k < kH; _k += 4) {          \
      _a0 = fmaf((S)[_k + 0], (W)[_k + 0], _a0);  \
      _a1 = fmaf((S)[_k + 1], (W)[_k + 1], _a1);  \
      _a2 = fmaf((S)[_k + 2], (W)[_k + 2], _a2);  \
      _a3 = fmaf((S)[_k + 3], (W)[_k + 3], _a3);  \
    }                                             \
    acc0 = (_a0 + _a1) + (_a2 + _a3);             \
  }

// ---------------- Kernel A: gi0[t][g] = bih0[g] + sum_f batch[t][f]*Wih0[g][f]
__global__ __launch_bounds__(256) void gi0_kernel(
    const float* __restrict__ batch, const float* __restrict__ Wih0,
    const float* __restrict__ bih0, float* __restrict__ gi0, int T) {
  __shared__ __align__(16) float w[kG * kF];
  __shared__ float bsh[kG];
  for (int i = threadIdx.x; i < kG * kF; i += blockDim.x) w[i] = Wih0[i];
  if (threadIdx.x < kG) bsh[threadIdx.x] = bih0[threadIdx.x];
  __syncthreads();
  int t = blockIdx.x * blockDim.x + threadIdx.x;
  if (t >= T) return;
  float acc[kG];
#pragma unroll
  for (int gg = 0; gg < kG; ++gg) acc[gg] = bsh[gg];
  const float* brow = batch + (size_t)t * kF;
  for (int f = 0; f < kF; f += 4) {
    const float4 b4 = *reinterpret_cast<const float4*>(brow + f);
#pragma unroll
    for (int gg = 0; gg < kG; ++gg) {
      const float4 w4 = *reinterpret_cast<const float4*>(&w[gg * kF + f]);
      acc[gg] = fmaf(b4.x, w4.x, acc[gg]);
      acc[gg] = fmaf(b4.y, w4.y, acc[gg]);
      acc[gg] = fmaf(b4.z, w4.z, acc[gg]);
      acc[gg] = fmaf(b4.w, w4.w, acc[gg]);
    }
  }
  float* orow = gi0 + (size_t)t * kG;
#pragma unroll
  for (int gg = 0; gg < kG; gg += 4) {
    *reinterpret_cast<float4*>(orow + gg) =
        make_float4(acc[gg], acc[gg + 1], acc[gg + 2], acc[gg + 3]);
  }
}

// ---------------- Kernel B: sequential recurrence, one wave, ZERO LDS ops.
// Row roles (per component a = lane&15): row0 = r-gate, row1 = z-dup,
// row2 = n-gate (computes hnew), row3 = z-gate. All cross-lane routing via
// permlane{16,32}-swap builtins (VALU). State hs: lane 16*l+a holds h[l][a].
__global__ __launch_bounds__(64)
__attribute__((amdgpu_waves_per_eu(1, 1)))
void seq_kernel(
    const float* __restrict__ Whh0, const float* __restrict__ bhh0,
    const float* __restrict__ Wih, const float* __restrict__ Whh,
    const float* __restrict__ bih, const float* __restrict__ bhh,
    const float* __restrict__ aW, const float* __restrict__ ab,
    const float* __restrict__ av, const float* __restrict__ avb,
    const float* __restrict__ gi0, float* __restrict__ topout, int T) {
  const int lane = threadIdx.x & 63;
  const int grp = lane >> 4;
  const int a = lane & 15;
  // gate row in [0,48): row0 -> r rows (0..15), rows1,3 -> z rows (16..31),
  // row2 -> n rows (32..47)
  const int gr = (grp == 0) ? a : (grp == 2 ? 32 + a : 16 + a);

  // --- per-lane weights (one gate row per lane per matrix) ---
  float Wh[kL][kH];  // Whh row gr, layers 0..3
  float Ux[3][kH];   // Wih row gr, layers 1..3
#pragma unroll
  for (int k = 0; k < kH; ++k) Wh[0][k] = Whh0[gr * kH + k];
#pragma unroll
  for (int l = 1; l < kL; ++l) {
#pragma unroll
    for (int k = 0; k < kH; ++k) {
      Wh[l][k] = Whh[((l - 1) * kG + gr) * kH + k];
      Ux[l - 1][k] = Wih[((l - 1) * kG + gr) * kH + k];
    }
  }
  float bh[kL], bi[3];
  bh[0] = bhh0[gr];
#pragma unroll
  for (int l = 1; l < kL; ++l) {
    bh[l] = bhh[(l - 1) * kG + gr];
    bi[l - 1] = bih[(l - 1) * kG + gr];
  }
  // attention params: head grp, unit a
  float aWr[kH];
#pragma unroll
  for (int k = 0; k < kH; ++k) aWr[k] = aW[(grp * kH + k) * kA + a];
  float abr = ab[grp * kA + a];
  float avr = av[grp * kA + a];
  float avbr = avb[grp];

  // pin loop-invariants into VGPRs
#pragma unroll
  for (int l = 0; l < kL; ++l) {
#pragma unroll
    for (int k = 0; k < kH; ++k) PIN(Wh[l][k]);
    PIN(bh[l]);
  }
#pragma unroll
  for (int l = 0; l < 3; ++l) {
#pragma unroll
    for (int k = 0; k < kH; ++k) PIN(Ux[l][k]);
    PIN(bi[l]);
  }
#pragma unroll
  for (int k = 0; k < kH; ++k) PIN(aWr[k]);
  PIN(abr); PIN(avr); PIN(avbr);

  float hs = 0.0f;
  // gi0 prefetch: one per-lane stream (row gr), depth 3
  const float* pG = gi0 + gr;
  float g0 = pG[0], g1 = pG[kG], g2 = pG[2 * kG];

  for (int t = 0; t < T; ++t) {
    const float gcur = g0;
    g0 = g1; g1 = g2;
    {
      int tn = t + 3;
      tn = tn < T ? tn : T - 1;
      g2 = pG[(size_t)tn * kG];
    }

    // holds for row2 (the hnew row), all via VALU swaps, off critical path
    const float h0 = swap_sum32(grp == 0 ? hs : 0.0f);          // row2 <- row0
    const float t1 = swap_sum16(grp == 1 ? hs : 0.0f);          // row0 <- row1
    const float h1 = swap_sum32(grp == 0 ? t1 : 0.0f);          // row2 <- row0
    const float h3 = swap_sum16(grp == 3 ? hs : 0.0f);          // row2 <- row3

    float xs[kH];   // broadcast copies of current layer output (uniform)
    float sc[kL];   // attention scores (uniform per row)
    float xg[kL];   // per-lane x_j[a] for the mix

#pragma unroll
    for (int l = 0; l < kL; ++l) {
      // broadcast prev state of this layer
      float hb[kH];
#pragma unroll
      for (int k = 0; k < kH; ++k) hb[k] = rl(hs, l * kH + k);
      // hb-slot: row0 ghr, rows1,3 ghz, row2 ghn
      float accH = bh[l]; DOT16(accH, hb, Wh[l]);
      // xs-slot: row0 gir, rows1,3 giz, row2 gin (layer 0 precomputed)
      float accX;
      if (l == 0) {
        accX = gcur;
      } else {
        accX = bi[l - 1]; DOT16(accX, xs, Ux[l - 1]);
      }
      const float sg = sigm(accX + accH);                // row0: r, rows1,3: z
      const float rv = swap_sum32(grp == 0 ? sg : 0.0f); // row2 <- r
      const float zv = swap_sum16(grp == 3 ? sg : 0.0f); // row2 <- z
      const float nt = tanh_f(fmaf(rv, accH, accX));     // row2: n
      const float hold = (l == 0) ? h0 : (l == 1) ? h1 : (l == 2) ? hs : h3;
      const float hnew = fmaf(zv, hold - nt, nt);        // valid in row2
      // broadcast x_l to scalars (from row2 lanes)
#pragma unroll
      for (int k = 0; k < kH; ++k) xs[k] = rl(hnew, 32 + k);
      // attention score s[grp][l]
      float d = abr; DOT16(d, xs, aWr);
      d = tanh_f(d);
      sc[l] = row_sum16(d * avr) + avbr;
      // route x_l[a] (row2) to all rows for the mix: ^32 then ^16
      xg[l] = swap_sum16(swap_sum32(grp == 2 ? hnew : 0.0f));
    }

    // masked softmax over j >= grp (uniform within each row)
    const float s0 = (grp == 0) ? sc[0] : -1e30f;
    const float s1 = (grp <= 1) ? sc[1] : -1e30f;
    const float s2 = (grp <= 2) ? sc[2] : -1e30f;
    const float s3 = sc[3];
    const float m = fmaxf(fmaxf(s0, s1), fmaxf(s2, s3));
    const float e0 = __builtin_amdgcn_exp2f((s0 - m) * kL2E);
    const float e1 = __builtin_amdgcn_exp2f((s1 - m) * kL2E);
    const float e2 = __builtin_amdgcn_exp2f((s2 - m) * kL2E);
    const float e3 = __builtin_amdgcn_exp2f((s3 - m) * kL2E);
    const float rden = fast_rcp((e0 + e1) + (e2 + e3));
    float num = e0 * xg[0];
    num = fmaf(e1, xg[1], num);
    num = fmaf(e2, xg[2], num);
    num = fmaf(e3, xg[3], num);
    hs = num * rden;   // lane 16*grp+a now holds h_new[grp][a]

    if (lane >= 48) topout[(size_t)t * kH + a] = hs;  // head-3 output
  }
}

// ---------------- Kernel C: out[t] = fc2( relu( fc1( top[t] ) ) )
__global__ __launch_bounds__(256) void head_kernel(
    const float* __restrict__ top, const float* __restrict__ fc1W,
    const float* __restrict__ fc1b, const float* __restrict__ fc2W,
    const float* __restrict__ fc2b, float* __restrict__ out, int T) {
  __shared__ __align__(16) float w1[32 * kH];
  __shared__ float b1[32], w2[32];
  for (int i = threadIdx.x; i < 32 * kH; i += blockDim.x) w1[i] = fc1W[i];
  if (threadIdx.x < 32) {
    b1[threadIdx.x] = fc1b[threadIdx.x];
    w2[threadIdx.x] = fc2W[threadIdx.x];
  }
  __syncthreads();
  int t = blockIdx.x * blockDim.x + threadIdx.x;
  if (t >= T) return;
  const float* hrow = top + (size_t)t * kH;
  float hv[kH];
#pragma unroll
  for (int k = 0; k < kH; k += 4) {
    const float4 h4 = *reinterpret_cast<const float4*>(hrow + k);
    hv[k] = h4.x; hv[k + 1] = h4.y; hv[k + 2] = h4.z; hv[k + 3] = h4.w;
  }
  float o = fc2b[0];
#pragma unroll
  for (int mth = 0; mth < 32; ++mth) {
    float acc = b1[mth];
#pragma unroll
    for (int k = 0; k < kH; ++k) acc = fmaf(hv[k], w1[mth * kH + k], acc);
    acc = fmaxf(acc, 0.0f);
    o = fmaf(acc, w2[mth], o);
  }
  out[t] = o;
}

extern "C" void kernel_launch(void* const* d_in, const int* in_sizes, int n_in,
                              void* d_out, int out_size, void* d_ws, size_t ws_size,
                              hipStream_t stream) {
  const float* batch = (const float*)d_in[0];
  const float* Wih0  = (const float*)d_in[1];
  const float* Whh0  = (const float*)d_in[2];
  const float* bih0  = (const float*)d_in[3];
  const float* bhh0  = (const float*)d_in[4];
  const float* Wih   = (const float*)d_in[5];
  const float* Whh   = (const float*)d_in[6];
  const float* bih   = (const float*)d_in[7];
  const float* bhh   = (const float*)d_in[8];
  const float* aW    = (const float*)d_in[9];
  const float* ab    = (const float*)d_in[10];
  const float* av    = (const float*)d_in[11];
  const float* avb   = (const float*)d_in[12];
  const float* fc1W  = (const float*)d_in[13];
  const float* fc1b  = (const float*)d_in[14];
  const float* fc2W  = (const float*)d_in[15];
  const float* fc2b  = (const float*)d_in[16];
  float* out = (float*)d_out;

  const int T = in_sizes[0] / kF;  // 131072

  // workspace layout: gi0 [T*48 f32] | top [T*16 f32]
  float* gi0 = (float*)d_ws;
  float* top = gi0 + (size_t)T * kG;

  const int blocks = (T + 255) / 256;
  gi0_kernel<<<blocks, 256, 0, stream>>>(batch, Wih0, bih0, gi0, T);
  seq_kernel<<<1, 64, 0, stream>>>(Whh0, bhh0, Wih, Whh, bih, bhh,
                                   aW, ab, av, avb, gi0, top, T);
  head_kernel<<<blocks, 256, 0, stream>>>(top, fc1W, fc1b, fc2W, fc2b, out, T);
}

// Round 8
// 154972.754 us; speedup vs baseline: 1.6652x; 1.0320x over previous
//
#include <hip/hip_runtime.h>
#include <cstddef>

namespace {
constexpr int kH = 16;   // hidden
constexpr int kL = 4;    // layers
constexpr int kF = 256;  // input features
constexpr int kA = 16;   // attention dim
constexpr int kG = 48;   // 3*H gates
}

// Pin a value into a VGPR at this point (opaque to the optimizer).
#define PIN(x) asm volatile("" : "+v"(x))

__device__ __forceinline__ float rl(float v, int lane) {
  return __int_as_float(__builtin_amdgcn_readlane(__float_as_int(v), lane));
}

// x[i] + x[i^32] / x[i] + x[i^16], via the gfx950 permlane-swap builtins.
// res0+res1 = own+partner under any complementary-half-swap convention.
#if defined(__has_builtin)
#if __has_builtin(__builtin_amdgcn_permlane16_swap) && __has_builtin(__builtin_amdgcn_permlane32_swap)
#define HAVE_PLSWAP 1
#endif
#endif

#ifdef HAVE_PLSWAP
__device__ __forceinline__ float swap_sum32(float x) {
  auto r = __builtin_amdgcn_permlane32_swap(__float_as_uint(x), __float_as_uint(x), false, false);
  return __uint_as_float(r[0]) + __uint_as_float(r[1]);
}
__device__ __forceinline__ float swap_sum16(float x) {
  auto r = __builtin_amdgcn_permlane16_swap(__float_as_uint(x), __float_as_uint(x), false, false);
  return __uint_as_float(r[0]) + __uint_as_float(r[1]);
}
#else
__device__ __forceinline__ float swap_sum32(float x) {
  return x + __shfl(x, (int)(threadIdx.x & 63) ^ 32, 64);
}
__device__ __forceinline__ float swap_sum16(float x) {
  return x + __shfl(x, (int)(threadIdx.x & 63) ^ 16, 64);
}
#endif

// add value rotated by N within each 16-lane row (DPP row_ror)
template <int CTRL>
__device__ __forceinline__ float ror_add(float x) {
  int r = __builtin_amdgcn_update_dpp(0, __float_as_int(x), CTRL, 0xF, 0xF, false);
  return x + __int_as_float(r);
}
__device__ __forceinline__ float row_sum16(float x) {
  x = ror_add<0x128>(x);  // ror 8
  x = ror_add<0x124>(x);  // ror 4
  x = ror_add<0x122>(x);  // ror 2
  x = ror_add<0x121>(x);  // ror 1
  return x;
}
__device__ __forceinline__ float fast_rcp(float x) { return __builtin_amdgcn_rcpf(x); }
constexpr float kL2E = 1.4426950408889634f;
__device__ __forceinline__ float sigm(float x) {
  return fast_rcp(1.0f + __builtin_amdgcn_exp2f(-kL2E * x));
}
__device__ __forceinline__ float tanh_f(float x) {
  return 1.0f - 2.0f * fast_rcp(1.0f + __builtin_amdgcn_exp2f((2.0f * kL2E) * x));
}

// 4-way split dot of 16 broadcast scalars against per-lane weights.
#define DOT16(acc0, S, W)                         \
  {                                               \
    float _a0 = (acc0), _a1 = 0.f, _a2 = 0.f, _a3 = 0.f; \
    _Pragma("unroll")                             \
    for (int _k = 0; _k < kH; _k += 4) {          \
      _a0 = fmaf((S)[_k + 0], (W)[_k + 0], _a0);  \
      _a1 = fmaf((S)[_k + 1], (W)[_k + 1], _a1);  \
      _a2 = fmaf((S)[_k + 2], (W)[_k + 2], _a2);  \
      _a3 = fmaf((S)[_k + 3], (W)[_k + 3], _a3);  \
    }                                             \
    acc0 = (_a0 + _a1) + (_a2 + _a3);             \
  }

// ---------------- Kernel A: gi0[t][g] = bih0[g] + sum_f batch[t][f]*Wih0[g][f]
// Also re-arms the heater flag (runs before seq_kernel in stream order).
__global__ __launch_bounds__(256) void gi0_kernel(
    const float* __restrict__ batch, const float* __restrict__ Wih0,
    const float* __restrict__ bih0, float* __restrict__ gi0, int T,
    int* flag) {
  if (flag && blockIdx.x == 0 && threadIdx.x == 0) {
    __hip_atomic_store(flag, 0, __ATOMIC_RELAXED, __HIP_MEMORY_SCOPE_AGENT);
  }
  __shared__ __align__(16) float w[kG * kF];
  __shared__ float bsh[kG];
  for (int i = threadIdx.x; i < kG * kF; i += blockDim.x) w[i] = Wih0[i];
  if (threadIdx.x < kG) bsh[threadIdx.x] = bih0[threadIdx.x];
  __syncthreads();
  int t = blockIdx.x * blockDim.x + threadIdx.x;
  if (t >= T) return;
  float acc[kG];
#pragma unroll
  for (int gg = 0; gg < kG; ++gg) acc[gg] = bsh[gg];
  const float* brow = batch + (size_t)t * kF;
  for (int f = 0; f < kF; f += 4) {
    const float4 b4 = *reinterpret_cast<const float4*>(brow + f);
#pragma unroll
    for (int gg = 0; gg < kG; ++gg) {
      const float4 w4 = *reinterpret_cast<const float4*>(&w[gg * kF + f]);
      acc[gg] = fmaf(b4.x, w4.x, acc[gg]);
      acc[gg] = fmaf(b4.y, w4.y, acc[gg]);
      acc[gg] = fmaf(b4.z, w4.z, acc[gg]);
      acc[gg] = fmaf(b4.w, w4.w, acc[gg]);
    }
  }
  float* orow = gi0 + (size_t)t * kG;
#pragma unroll
  for (int gg = 0; gg < kG; gg += 4) {
    *reinterpret_cast<float4*>(orow + gg) =
        make_float4(acc[gg], acc[gg + 1], acc[gg + 2], acc[gg + 3]);
  }
}

// ---------------- Kernel B: block 0 = the R7 sequential recurrence (unchanged).
// Blocks 1..N-1 = DVFS heaters: register-only FMA spin until block 0 sets the
// done-flag (or a fixed CAP of iterations). They write nothing.
__global__ __launch_bounds__(64)
__attribute__((amdgpu_waves_per_eu(1, 1)))
void seq_kernel(
    const float* __restrict__ Whh0, const float* __restrict__ bhh0,
    const float* __restrict__ Wih, const float* __restrict__ Whh,
    const float* __restrict__ bih, const float* __restrict__ bhh,
    const float* __restrict__ aW, const float* __restrict__ ab,
    const float* __restrict__ av, const float* __restrict__ avb,
    const float* __restrict__ gi0, float* __restrict__ topout, int T,
    int* flag, int heater_outer) {
  const int lane = threadIdx.x & 63;

  if (blockIdx.x != 0) {
    // ---- heater: 8 independent FMA chains, poll flag every ~512 cycles ----
    float c0 = 1.0f + lane * 1e-6f, c1 = 1.1f, c2 = 1.2f, c3 = 1.3f;
    float c4 = 1.4f, c5 = 1.5f, c6 = 1.6f, c7 = 1.7f;
    const float m = 0.999999f, b = 1e-7f;
    for (int i = 0; i < heater_outer; ++i) {
#pragma unroll
      for (int j = 0; j < 32; ++j) {
        c0 = fmaf(c0, m, b); c1 = fmaf(c1, m, b);
        c2 = fmaf(c2, m, b); c3 = fmaf(c3, m, b);
        c4 = fmaf(c4, m, b); c5 = fmaf(c5, m, b);
        c6 = fmaf(c6, m, b); c7 = fmaf(c7, m, b);
      }
      if (__hip_atomic_load(flag, __ATOMIC_RELAXED, __HIP_MEMORY_SCOPE_AGENT)) break;
    }
    float s = ((c0 + c1) + (c2 + c3)) + ((c4 + c5) + (c6 + c7));
    asm volatile("" :: "v"(s));  // keep alive, no side effects
    return;
  }

  const int grp = lane >> 4;
  const int a = lane & 15;
  // gate row in [0,48): row0 -> r rows, rows1,3 -> z rows, row2 -> n rows
  const int gr = (grp == 0) ? a : (grp == 2 ? 32 + a : 16 + a);

  // --- per-lane weights (one gate row per lane per matrix) ---
  float Wh[kL][kH];  // Whh row gr, layers 0..3
  float Ux[3][kH];   // Wih row gr, layers 1..3
#pragma unroll
  for (int k = 0; k < kH; ++k) Wh[0][k] = Whh0[gr * kH + k];
#pragma unroll
  for (int l = 1; l < kL; ++l) {
#pragma unroll
    for (int k = 0; k < kH; ++k) {
      Wh[l][k] = Whh[((l - 1) * kG + gr) * kH + k];
      Ux[l - 1][k] = Wih[((l - 1) * kG + gr) * kH + k];
    }
  }
  float bh[kL], bi[3];
  bh[0] = bhh0[gr];
#pragma unroll
  for (int l = 1; l < kL; ++l) {
    bh[l] = bhh[(l - 1) * kG + gr];
    bi[l - 1] = bih[(l - 1) * kG + gr];
  }
  // attention params: head grp, unit a
  float aWr[kH];
#pragma unroll
  for (int k = 0; k < kH; ++k) aWr[k] = aW[(grp * kH + k) * kA + a];
  float abr = ab[grp * kA + a];
  float avr = av[grp * kA + a];
  float avbr = avb[grp];

  // pin loop-invariants into VGPRs
#pragma unroll
  for (int l = 0; l < kL; ++l) {
#pragma unroll
    for (int k = 0; k < kH; ++k) PIN(Wh[l][k]);
    PIN(bh[l]);
  }
#pragma unroll
  for (int l = 0; l < 3; ++l) {
#pragma unroll
    for (int k = 0; k < kH; ++k) PIN(Ux[l][k]);
    PIN(bi[l]);
  }
#pragma unroll
  for (int k = 0; k < kH; ++k) PIN(aWr[k]);
  PIN(abr); PIN(avr); PIN(avbr);

  float hs = 0.0f;
  // gi0 prefetch: one per-lane stream (row gr), depth 3
  const float* pG = gi0 + gr;
  float g0 = pG[0], g1 = pG[kG], g2 = pG[2 * kG];

  for (int t = 0; t < T; ++t) {
    const float gcur = g0;
    g0 = g1; g1 = g2;
    {
      int tn = t + 3;
      tn = tn < T ? tn : T - 1;
      g2 = pG[(size_t)tn * kG];
    }

    // holds for row2 (the hnew row), all via VALU swaps, off critical path
    const float h0 = swap_sum32(grp == 0 ? hs : 0.0f);          // row2 <- row0
    const float t1 = swap_sum16(grp == 1 ? hs : 0.0f);          // row0 <- row1
    const float h1 = swap_sum32(grp == 0 ? t1 : 0.0f);          // row2 <- row0
    const float h3 = swap_sum16(grp == 3 ? hs : 0.0f);          // row2 <- row3

    float xs[kH];   // broadcast copies of current layer output (uniform)
    float sc[kL];   // attention scores (uniform per row)
    float xg[kL];   // per-lane x_j[a] for the mix

#pragma unroll
    for (int l = 0; l < kL; ++l) {
      // broadcast prev state of this layer
      float hb[kH];
#pragma unroll
      for (int k = 0; k < kH; ++k) hb[k] = rl(hs, l * kH + k);
      // hb-slot: row0 ghr, rows1,3 ghz, row2 ghn
      float accH = bh[l]; DOT16(accH, hb, Wh[l]);
      // xs-slot: row0 gir, rows1,3 giz, row2 gin (layer 0 precomputed)
      float accX;
      if (l == 0) {
        accX = gcur;
      } else {
        accX = bi[l - 1]; DOT16(accX, xs, Ux[l - 1]);
      }
      const float sg = sigm(accX + accH);                // row0: r, rows1,3: z
      const float rv = swap_sum32(grp == 0 ? sg : 0.0f); // row2 <- r
      const float zv = swap_sum16(grp == 3 ? sg : 0.0f); // row2 <- z
      const float nt = tanh_f(fmaf(rv, accH, accX));     // row2: n
      const float hold = (l == 0) ? h0 : (l == 1) ? h1 : (l == 2) ? hs : h3;
      const float hnew = fmaf(zv, hold - nt, nt);        // valid in row2
      // broadcast x_l to scalars (from row2 lanes)
#pragma unroll
      for (int k = 0; k < kH; ++k) xs[k] = rl(hnew, 32 + k);
      // attention score s[grp][l]
      float d = abr; DOT16(d, xs, aWr);
      d = tanh_f(d);
      sc[l] = row_sum16(d * avr) + avbr;
      // route x_l[a] (row2) to all rows for the mix: ^32 then ^16
      xg[l] = swap_sum16(swap_sum32(grp == 2 ? hnew : 0.0f));
    }

    // masked softmax over j >= grp (uniform within each row)
    const float s0 = (grp == 0) ? sc[0] : -1e30f;
    const float s1 = (grp <= 1) ? sc[1] : -1e30f;
    const float s2 = (grp <= 2) ? sc[2] : -1e30f;
    const float s3 = sc[3];
    const float m = fmaxf(fmaxf(s0, s1), fmaxf(s2, s3));
    const float e0 = __builtin_amdgcn_exp2f((s0 - m) * kL2E);
    const float e1 = __builtin_amdgcn_exp2f((s1 - m) * kL2E);
    const float e2 = __builtin_amdgcn_exp2f((s2 - m) * kL2E);
    const float e3 = __builtin_amdgcn_exp2f((s3 - m) * kL2E);
    const float rden = fast_rcp((e0 + e1) + (e2 + e3));
    float num = e0 * xg[0];
    num = fmaf(e1, xg[1], num);
    num = fmaf(e2, xg[2], num);
    num = fmaf(e3, xg[3], num);
    hs = num * rden;   // lane 16*grp+a now holds h_new[grp][a]

    if (lane >= 48) topout[(size_t)t * kH + a] = hs;  // head-3 output
  }

  if (flag && lane == 0) {
    __hip_atomic_store(flag, 1, __ATOMIC_RELAXED, __HIP_MEMORY_SCOPE_AGENT);
  }
}

// ---------------- Kernel C: out[t] = fc2( relu( fc1( top[t] ) ) )
__global__ __launch_bounds__(256) void head_kernel(
    const float* __restrict__ top, const float* __restrict__ fc1W,
    const float* __restrict__ fc1b, const float* __restrict__ fc2W,
    const float* __restrict__ fc2b, float* __restrict__ out, int T) {
  __shared__ __align__(16) float w1[32 * kH];
  __shared__ float b1[32], w2[32];
  for (int i = threadIdx.x; i < 32 * kH; i += blockDim.x) w1[i] = fc1W[i];
  if (threadIdx.x < 32) {
    b1[threadIdx.x] = fc1b[threadIdx.x];
    w2[threadIdx.x] = fc2W[threadIdx.x];
  }
  __syncthreads();
  int t = blockIdx.x * blockDim.x + threadIdx.x;
  if (t >= T) return;
  const float* hrow = top + (size_t)t * kH;
  float hv[kH];
#pragma unroll
  for (int k = 0; k < kH; k += 4) {
    const float4 h4 = *reinterpret_cast<const float4*>(hrow + k);
    hv[k] = h4.x; hv[k + 1] = h4.y; hv[k + 2] = h4.z; hv[k + 3] = h4.w;
  }
  float o = fc2b[0];
#pragma unroll
  for (int mth = 0; mth < 32; ++mth) {
    float acc = b1[mth];
#pragma unroll
    for (int k = 0; k < kH; ++k) acc = fmaf(hv[k], w1[mth * kH + k], acc);
    acc = fmaxf(acc, 0.0f);
    o = fmaf(acc, w2[mth], o);
  }
  out[t] = o;
}

extern "C" void kernel_launch(void* const* d_in, const int* in_sizes, int n_in,
                              void* d_out, int out_size, void* d_ws, size_t ws_size,
                              hipStream_t stream) {
  const float* batch = (const float*)d_in[0];
  const float* Wih0  = (const float*)d_in[1];
  const float* Whh0  = (const float*)d_in[2];
  const float* bih0  = (const float*)d_in[3];
  const float* bhh0  = (const float*)d_in[4];
  const float* Wih   = (const float*)d_in[5];
  const float* Whh   = (const float*)d_in[6];
  const float* bih   = (const float*)d_in[7];
  const float* bhh   = (const float*)d_in[8];
  const float* aW    = (const float*)d_in[9];
  const float* ab    = (const float*)d_in[10];
  const float* av    = (const float*)d_in[11];
  const float* avb   = (const float*)d_in[12];
  const float* fc1W  = (const float*)d_in[13];
  const float* fc1b  = (const float*)d_in[14];
  const float* fc2W  = (const float*)d_in[15];
  const float* fc2b  = (const float*)d_in[16];
  float* out = (float*)d_out;

  const int T = in_sizes[0] / kF;  // 131072

  // workspace layout: gi0 [T*48 f32] | top [T*16 f32] | flag [1 i32, optional]
  float* gi0 = (float*)d_ws;
  float* top = gi0 + (size_t)T * kG;
  const size_t core_bytes = (size_t)T * (kG + kH) * sizeof(float);
  int* flag = nullptr;
  int seq_blocks = 1;
  if (ws_size >= core_bytes + sizeof(int)) {
    flag = (int*)((char*)d_ws + core_bytes);
    seq_blocks = 256;  // block 0 = recurrence, 1..255 = DVFS heaters
  }
  // heater CAP: ~150 ms at 2.4 GHz if the flag never arrives
  const int heater_outer = 300000;

  const int blocks = (T + 255) / 256;
  gi0_kernel<<<blocks, 256, 0, stream>>>(batch, Wih0, bih0, gi0, T, flag);
  seq_kernel<<<seq_blocks, 64, 0, stream>>>(Whh0, bhh0, Wih, Whh, bih, bhh,
                                            aW, ab, av, avb, gi0, top, T,
                                            flag, heater_outer);
  head_kernel<<<blocks, 256, 0, stream>>>(top, fc1W, fc1b, fc2W, fc2b, out, T);
}

// Round 9
// 143844.153 us; speedup vs baseline: 1.7940x; 1.0774x over previous
//
#include <hip/hip_runtime.h>
#include <cstddef>

namespace {
constexpr int kH = 16;   // hidden
constexpr int kL = 4;    // layers
constexpr int kF = 256;  // input features
constexpr int kA = 16;   // attention dim
constexpr int kG = 48;   // 3*H gates
}

// Pin a value into a VGPR at this point (opaque to the optimizer).
#define PIN(x) asm volatile("" : "+v"(x))

// x[i] + x[i^32] / x[i] + x[i^16], via the gfx950 permlane-swap builtins.
#if defined(__has_builtin)
#if __has_builtin(__builtin_amdgcn_permlane16_swap) && __has_builtin(__builtin_amdgcn_permlane32_swap)
#define HAVE_PLSWAP 1
#endif
#endif

#ifdef HAVE_PLSWAP
__device__ __forceinline__ float swap_sum32(float x) {
  auto r = __builtin_amdgcn_permlane32_swap(__float_as_uint(x), __float_as_uint(x), false, false);
  return __uint_as_float(r[0]) + __uint_as_float(r[1]);
}
__device__ __forceinline__ float swap_sum16(float x) {
  auto r = __builtin_amdgcn_permlane16_swap(__float_as_uint(x), __float_as_uint(x), false, false);
  return __uint_as_float(r[0]) + __uint_as_float(r[1]);
}
#else
__device__ __forceinline__ float swap_sum32(float x) {
  return x + __shfl(x, (int)(threadIdx.x & 63) ^ 32, 64);
}
__device__ __forceinline__ float swap_sum16(float x) {
  return x + __shfl(x, (int)(threadIdx.x & 63) ^ 16, 64);
}
#endif

// add value rotated by N within each 16-lane row (DPP row_ror)
template <int CTRL>
__device__ __forceinline__ float ror_add(float x) {
  int r = __builtin_amdgcn_update_dpp(0, __float_as_int(x), CTRL, 0xF, 0xF, false);
  return x + __int_as_float(r);
}
__device__ __forceinline__ float row_sum16(float x) {
  x = ror_add<0x128>(x);  // ror 8
  x = ror_add<0x124>(x);  // ror 4
  x = ror_add<0x122>(x);  // ror 2
  x = ror_add<0x121>(x);  // ror 1
  return x;
}
__device__ __forceinline__ float fast_rcp(float x) { return __builtin_amdgcn_rcpf(x); }
constexpr float kL2E = 1.4426950408889634f;
__device__ __forceinline__ float sigm(float x) {
  return fast_rcp(1.0f + __builtin_amdgcn_exp2f(-kL2E * x));
}
__device__ __forceinline__ float tanh_f(float x) {
  return 1.0f - 2.0f * fast_rcp(1.0f + __builtin_amdgcn_exp2f((2.0f * kL2E) * x));
}

// ---- rotate-dot: acc = bias + sum_j ror(h, j) * w[j], w pre-rotated so that
// w[j][lane a] = W[row(a)][(a - j) & 15]. row_ror:n => lane i reads lane
// (i-n)&15 (same convention as HIP __shfl_up -> row_shr). 16 lanes per row,
// zero cross-lane readlanes, zero SGPR hazards. Volatile asm pins the plain
// v_fma + s_nop ahead of the first DPP read of h (DPP wait-state hazard).
#define FMAC_ROR(acc, h, w, J)                                            \
  asm volatile("v_fmac_f32_dpp %0, %1, %2 row_ror:" #J                    \
               " row_mask:0xf bank_mask:0xf"                              \
               : "+v"(acc) : "v"(h), "v"(w))
#define MUL_ROR(dst, h, w, J)                                             \
  asm volatile("v_mul_f32_dpp %0, %1, %2 row_ror:" #J                     \
               " row_mask:0xf bank_mask:0xf"                              \
               : "=v"(dst) : "v"(h), "v"(w))

__device__ __forceinline__ float dot16r(const float* w, float h, float bias) {
  float a0, a1, a2, a3;
  asm volatile("v_fma_f32 %0, %1, %2, %3" : "=v"(a0) : "v"(h), "v"(w[0]), "v"(bias));
  asm volatile("s_nop 0" ::: );  // >=2 slots between h's producer and DPP read
  MUL_ROR(a1, h, w[1], 1);
  MUL_ROR(a2, h, w[2], 2);
  MUL_ROR(a3, h, w[3], 3);
  FMAC_ROR(a0, h, w[4], 4);
  FMAC_ROR(a1, h, w[5], 5);
  FMAC_ROR(a2, h, w[6], 6);
  FMAC_ROR(a3, h, w[7], 7);
  FMAC_ROR(a0, h, w[8], 8);
  FMAC_ROR(a1, h, w[9], 9);
  FMAC_ROR(a2, h, w[10], 10);
  FMAC_ROR(a3, h, w[11], 11);
  FMAC_ROR(a0, h, w[12], 12);
  FMAC_ROR(a1, h, w[13], 13);
  FMAC_ROR(a2, h, w[14], 14);
  FMAC_ROR(a3, h, w[15], 15);
  return (a0 + a1) + (a2 + a3);
}

// ---------------- Kernel A: gi0[t][g] = bih0[g] + sum_f batch[t][f]*Wih0[g][f]
__global__ __launch_bounds__(256) void gi0_kernel(
    const float* __restrict__ batch, const float* __restrict__ Wih0,
    const float* __restrict__ bih0, float* __restrict__ gi0, int T) {
  __shared__ __align__(16) float w[kG * kF];
  __shared__ float bsh[kG];
  for (int i = threadIdx.x; i < kG * kF; i += blockDim.x) w[i] = Wih0[i];
  if (threadIdx.x < kG) bsh[threadIdx.x] = bih0[threadIdx.x];
  __syncthreads();
  int t = blockIdx.x * blockDim.x + threadIdx.x;
  if (t >= T) return;
  float acc[kG];
#pragma unroll
  for (int gg = 0; gg < kG; ++gg) acc[gg] = bsh[gg];
  const float* brow = batch + (size_t)t * kF;
  for (int f = 0; f < kF; f += 4) {
    const float4 b4 = *reinterpret_cast<const float4*>(brow + f);
#pragma unroll
    for (int gg = 0; gg < kG; ++gg) {
      const float4 w4 = *reinterpret_cast<const float4*>(&w[gg * kF + f]);
      acc[gg] = fmaf(b4.x, w4.x, acc[gg]);
      acc[gg] = fmaf(b4.y, w4.y, acc[gg]);
      acc[gg] = fmaf(b4.z, w4.z, acc[gg]);
      acc[gg] = fmaf(b4.w, w4.w, acc[gg]);
    }
  }
  float* orow = gi0 + (size_t)t * kG;
#pragma unroll
  for (int gg = 0; gg < kG; gg += 4) {
    *reinterpret_cast<float4*>(orow + gg) =
        make_float4(acc[gg], acc[gg + 1], acc[gg + 2], acc[gg + 3]);
  }
}

// ---------------- Kernel B: sequential recurrence, one wave, zero readlane.
// Row roles: row0 = r-gate, rows1,3 = z-gate, row2 = n-gate (computes hnew).
// Replicated state hq[l] = h[l][a] in every lane; gate dots are 16-lane DPP
// rotate-dots against pre-rotated per-lane weight rows. Routing (R7-verified):
// r row0->row2 (^32), z row3->row2 (^16), replication ladders via both swaps.
__global__ __launch_bounds__(64)
__attribute__((amdgpu_waves_per_eu(1, 1)))
void seq_kernel(
    const float* __restrict__ Whh0, const float* __restrict__ bhh0,
    const float* __restrict__ Wih, const float* __restrict__ Whh,
    const float* __restrict__ bih, const float* __restrict__ bhh,
    const float* __restrict__ aW, const float* __restrict__ ab,
    const float* __restrict__ av, const float* __restrict__ avb,
    const float* __restrict__ gi0, float* __restrict__ topout, int T) {
  const int lane = threadIdx.x & 63;
  const int grp = lane >> 4;
  const int a = lane & 15;
  // gate row in [0,48): row0 -> r rows, rows1,3 -> z rows, row2 -> n rows
  const int gr = (grp == 0) ? a : (grp == 2 ? 32 + a : 16 + a);

  // --- per-lane PRE-ROTATED weight rows ---
  float Wh[kL][kH];  // Whh row gr (rotated), layers 0..3
  float Ux[3][kH];   // Wih row gr (rotated), layers 1..3
  float aWj[kH];     // attention column a (rotated over k)
#pragma unroll
  for (int j = 0; j < kH; ++j) {
    const int idx = (a - j) & 15;
    Wh[0][j] = Whh0[gr * kH + idx];
#pragma unroll
    for (int l = 1; l < kL; ++l) {
      Wh[l][j] = Whh[((l - 1) * kG + gr) * kH + idx];
      Ux[l - 1][j] = Wih[((l - 1) * kG + gr) * kH + idx];
    }
    aWj[j] = aW[(grp * kH + idx) * kA + a];
  }
  float bh[kL], bi[3];
  bh[0] = bhh0[gr];
#pragma unroll
  for (int l = 1; l < kL; ++l) {
    bh[l] = bhh[(l - 1) * kG + gr];
    bi[l - 1] = bih[(l - 1) * kG + gr];
  }
  float abr = ab[grp * kA + a];
  float avr = av[grp * kA + a];
  float avbr = avb[grp];

  // pin loop-invariants into VGPRs
#pragma unroll
  for (int l = 0; l < kL; ++l) {
#pragma unroll
    for (int k = 0; k < kH; ++k) PIN(Wh[l][k]);
    PIN(bh[l]);
  }
#pragma unroll
  for (int l = 0; l < 3; ++l) {
#pragma unroll
    for (int k = 0; k < kH; ++k) PIN(Ux[l][k]);
    PIN(bi[l]);
  }
#pragma unroll
  for (int k = 0; k < kH; ++k) PIN(aWj[k]);
  PIN(abr); PIN(avr); PIN(avbr);

  float hs = 0.0f;  // packed state: lane 16*l+a holds h[l][a]
  // gi0 prefetch: one per-lane stream (row gr), depth 3
  const float* pG = gi0 + gr;
  float g0 = pG[0], g1 = pG[kG], g2 = pG[2 * kG];

  for (int t = 0; t < T; ++t) {
    const float gcur = g0;
    g0 = g1; g1 = g2;
    {
      int tn = t + 3;
      tn = tn < T ? tn : T - 1;
      g2 = pG[(size_t)tn * kG];
    }

    // replicate each layer's state to all lanes: hq[l] = h[l][a] everywhere
    float hq[kL];
    hq[0] = swap_sum16(swap_sum32(grp == 0 ? hs : 0.0f));
    hq[1] = swap_sum32(swap_sum16(grp == 1 ? hs : 0.0f));
    hq[2] = swap_sum16(swap_sum32(grp == 2 ? hs : 0.0f));
    hq[3] = swap_sum32(swap_sum16(grp == 3 ? hs : 0.0f));

    float xg[kL];   // replicated layer outputs x_l[a]
    float sc[kL];   // attention scores (uniform per row)

#pragma unroll
    for (int l = 0; l < kL; ++l) {
      // hidden dot: row0 ghr, rows1,3 ghz, row2 ghn  (rotate-dot, no readlane)
      const float accH = dot16r(Wh[l], hq[l], bh[l]);
      // input dot: row0 gir, rows1,3 giz, row2 gin (layer 0 precomputed)
      const float accX = (l == 0) ? gcur : dot16r(Ux[l - 1], xg[l - 1], bi[l - 1]);
      const float sg = sigm(accX + accH);                // row0: r, rows1,3: z
      const float rv = swap_sum32(grp == 0 ? sg : 0.0f); // row2 <- r
      const float zv = swap_sum16(grp == 3 ? sg : 0.0f); // row2 <- z
      const float nt = tanh_f(fmaf(rv, accH, accX));     // row2: n
      const float hnew = fmaf(zv, hq[l] - nt, nt);       // valid in row2
      // replicate x_l to all lanes (row2 -> all)
      xg[l] = swap_sum16(swap_sum32(grp == 2 ? hnew : 0.0f));
      // attention score s[grp][l]: d = tanh(aW . x_l + ab), s = v.d + vb
      const float d = tanh_f(dot16r(aWj, xg[l], abr));
      sc[l] = row_sum16(d * avr) + avbr;
    }

    // masked softmax over j >= grp (uniform within each row)
    const float s0 = (grp == 0) ? sc[0] : -1e30f;
    const float s1 = (grp <= 1) ? sc[1] : -1e30f;
    const float s2 = (grp <= 2) ? sc[2] : -1e30f;
    const float s3 = sc[3];
    const float m = fmaxf(fmaxf(s0, s1), fmaxf(s2, s3));
    const float e0 = __builtin_amdgcn_exp2f((s0 - m) * kL2E);
    const float e1 = __builtin_amdgcn_exp2f((s1 - m) * kL2E);
    const float e2 = __builtin_amdgcn_exp2f((s2 - m) * kL2E);
    const float e3 = __builtin_amdgcn_exp2f((s3 - m) * kL2E);
    const float rden = fast_rcp((e0 + e1) + (e2 + e3));
    float num = e0 * xg[0];
    num = fmaf(e1, xg[1], num);
    num = fmaf(e2, xg[2], num);
    num = fmaf(e3, xg[3], num);
    hs = num * rden;   // lane 16*grp+a holds h_new[grp][a]

    if (lane >= 48) topout[(size_t)t * kH + a] = hs;  // head-3 output
  }
}

// ---------------- Kernel C: out[t] = fc2( relu( fc1( top[t] ) ) )
__global__ __launch_bounds__(256) void head_kernel(
    const float* __restrict__ top, const float* __restrict__ fc1W,
    const float* __restrict__ fc1b, const float* __restrict__ fc2W,
    const float* __restrict__ fc2b, float* __restrict__ out, int T) {
  __shared__ __align__(16) float w1[32 * kH];
  __shared__ float b1[32], w2[32];
  for (int i = threadIdx.x; i < 32 * kH; i += blockDim.x) w1[i] = fc1W[i];
  if (threadIdx.x < 32) {
    b1[threadIdx.x] = fc1b[threadIdx.x];
    w2[threadIdx.x] = fc2W[threadIdx.x];
  }
  __syncthreads();
  int t = blockIdx.x * blockDim.x + threadIdx.x;
  if (t >= T) return;
  const float* hrow = top + (size_t)t * kH;
  float hv[kH];
#pragma unroll
  for (int k = 0; k < kH; k += 4) {
    const float4 h4 = *reinterpret_cast<const float4*>(hrow + k);
    hv[k] = h4.x; hv[k + 1] = h4.y; hv[k + 2] = h4.z; hv[k + 3] = h4.w;
  }
  float o = fc2b[0];
#pragma unroll
  for (int mth = 0; mth < 32; ++mth) {
    float acc = b1[mth];
#pragma unroll
    for (int k = 0; k < kH; ++k) acc = fmaf(hv[k], w1[mth * kH + k], acc);
    acc = fmaxf(acc, 0.0f);
    o = fmaf(acc, w2[mth], o);
  }
  out[t] = o;
}

extern "C" void kernel_launch(void* const* d_in, const int* in_sizes, int n_in,
                              void* d_out, int out_size, void* d_ws, size_t ws_size,
                              hipStream_t stream) {
  const float* batch = (const float*)d_in[0];
  const float* Wih0  = (const float*)d_in[1];
  const float* Whh0  = (const float*)d_in[2];
  const float* bih0  = (const float*)d_in[3];
  const float* bhh0  = (const float*)d_in[4];
  const float* Wih   = (const float*)d_in[5];
  const float* Whh   = (const float*)d_in[6];
  const float* bih   = (const float*)d_in[7];
  const float* bhh   = (const float*)d_in[8];
  const float* aW    = (const float*)d_in[9];
  const float* ab    = (const float*)d_in[10];
  const float* av    = (const float*)d_in[11];
  const float* avb   = (const float*)d_in[12];
  const float* fc1W  = (const float*)d_in[13];
  const float* fc1b  = (const float*)d_in[14];
  const float* fc2W  = (const float*)d_in[15];
  const float* fc2b  = (const float*)d_in[16];
  float* out = (float*)d_out;

  const int T = in_sizes[0] / kF;  // 131072

  // workspace layout: gi0 [T*48 f32] | top [T*16 f32]
  float* gi0 = (float*)d_ws;
  float* top = gi0 + (size_t)T * kG;

  const int blocks = (T + 255) / 256;
  gi0_kernel<<<blocks, 256, 0, stream>>>(batch, Wih0, bih0, gi0, T);
  seq_kernel<<<1, 64, 0, stream>>>(Whh0, bhh0, Wih, Whh, bih, bhh,
                                   aW, ab, av, avb, gi0, top, T);
  head_kernel<<<blocks, 256, 0, stream>>>(top, fc1W, fc1b, fc2W, fc2b, out, T);
}

// Round 10
// 128255.286 us; speedup vs baseline: 2.0121x; 1.1215x over previous
//
#include <hip/hip_runtime.h>
#include <cstddef>

namespace {
constexpr int kH = 16;   // hidden
constexpr int kL = 4;    // layers
constexpr int kF = 256;  // input features
constexpr int kA = 16;   // attention dim
constexpr int kG = 48;   // 3*H gates
}

// Pin a value into a VGPR at this point (opaque to the optimizer).
#define PIN(x) asm volatile("" : "+v"(x))

#if defined(__has_builtin)
#if __has_builtin(__builtin_amdgcn_permlane16_swap) && __has_builtin(__builtin_amdgcn_permlane32_swap)
#define HAVE_PLSWAP 1
#endif
#endif

#ifdef HAVE_PLSWAP
__device__ __forceinline__ float swap_sum32(float x) {
  auto r = __builtin_amdgcn_permlane32_swap(__float_as_uint(x), __float_as_uint(x), false, false);
  return __uint_as_float(r[0]) + __uint_as_float(r[1]);
}
__device__ __forceinline__ float swap_sum16(float x) {
  auto r = __builtin_amdgcn_permlane16_swap(__float_as_uint(x), __float_as_uint(x), false, false);
  return __uint_as_float(r[0]) + __uint_as_float(r[1]);
}
#else
__device__ __forceinline__ float swap_sum32(float x) {
  return x + __shfl(x, (int)(threadIdx.x & 63) ^ 32, 64);
}
__device__ __forceinline__ float swap_sum16(float x) {
  return x + __shfl(x, (int)(threadIdx.x & 63) ^ 16, 64);
}
#endif

// add value rotated by N within each 16-lane row (DPP row_ror)
template <int CTRL>
__device__ __forceinline__ float ror_add(float x) {
  int r = __builtin_amdgcn_update_dpp(0, __float_as_int(x), CTRL, 0xF, 0xF, false);
  return x + __int_as_float(r);
}
__device__ __forceinline__ float row_sum16(float x) {
  x = ror_add<0x128>(x);  // ror 8
  x = ror_add<0x124>(x);  // ror 4
  x = ror_add<0x122>(x);  // ror 2
  x = ror_add<0x121>(x);  // ror 1
  return x;
}
__device__ __forceinline__ float fast_rcp(float x) { return __builtin_amdgcn_rcpf(x); }
constexpr float kL2E = 1.4426950408889634f;
__device__ __forceinline__ float sigm(float x) {
  return fast_rcp(1.0f + __builtin_amdgcn_exp2f(-kL2E * x));
}
__device__ __forceinline__ float tanh_f(float x) {
  return 1.0f - 2.0f * fast_rcp(1.0f + __builtin_amdgcn_exp2f((2.0f * kL2E) * x));
}

// rotate-dot (R9-verified): acc = bias + sum_j ror(h, j) * w[j],
// w pre-rotated: w[j][lane a] = W[row(a)][(a - j) & 15].
#define FMAC_ROR(acc, h, w, J)                                            \
  asm volatile("v_fmac_f32_dpp %0, %1, %2 row_ror:" #J                    \
               " row_mask:0xf bank_mask:0xf"                              \
               : "+v"(acc) : "v"(h), "v"(w))
#define MUL_ROR(dst, h, w, J)                                             \
  asm volatile("v_mul_f32_dpp %0, %1, %2 row_ror:" #J                     \
               " row_mask:0xf bank_mask:0xf"                              \
               : "=v"(dst) : "v"(h), "v"(w))

__device__ __forceinline__ float dot16r(const float* w, float h, float bias) {
  float a0, a1, a2, a3;
  asm volatile("v_fma_f32 %0, %1, %2, %3" : "=v"(a0) : "v"(h), "v"(w[0]), "v"(bias));
  asm volatile("s_nop 0" ::: );
  MUL_ROR(a1, h, w[1], 1);
  MUL_ROR(a2, h, w[2], 2);
  MUL_ROR(a3, h, w[3], 3);
  FMAC_ROR(a0, h, w[4], 4);
  FMAC_ROR(a1, h, w[5], 5);
  FMAC_ROR(a2, h, w[6], 6);
  FMAC_ROR(a3, h, w[7], 7);
  FMAC_ROR(a0, h, w[8], 8);
  FMAC_ROR(a1, h, w[9], 9);
  FMAC_ROR(a2, h, w[10], 10);
  FMAC_ROR(a3, h, w[11], 11);
  FMAC_ROR(a0, h, w[12], 12);
  FMAC_ROR(a1, h, w[13], 13);
  FMAC_ROR(a2, h, w[14], 14);
  FMAC_ROR(a3, h, w[15], 15);
  return (a0 + a1) + (a2 + a3);
}

// ---------------- Kernel A: gi0T[g][t] = bih0[g] + sum_f batch[t][f]*Wih0[g][f]
// TRANSPOSED output: per-gate-row contiguous in t (seq reads float4 over t).
__global__ __launch_bounds__(256) void gi0_kernel(
    const float* __restrict__ batch, const float* __restrict__ Wih0,
    const float* __restrict__ bih0, float* __restrict__ gi0T, int T) {
  __shared__ __align__(16) float w[kG * kF];
  __shared__ float bsh[kG];
  for (int i = threadIdx.x; i < kG * kF; i += blockDim.x) w[i] = Wih0[i];
  if (threadIdx.x < kG) bsh[threadIdx.x] = bih0[threadIdx.x];
  __syncthreads();
  int t = blockIdx.x * blockDim.x + threadIdx.x;
  if (t >= T) return;
  float acc[kG];
#pragma unroll
  for (int gg = 0; gg < kG; ++gg) acc[gg] = bsh[gg];
  const float* brow = batch + (size_t)t * kF;
  for (int f = 0; f < kF; f += 4) {
    const float4 b4 = *reinterpret_cast<const float4*>(brow + f);
#pragma unroll
    for (int gg = 0; gg < kG; ++gg) {
      const float4 w4 = *reinterpret_cast<const float4*>(&w[gg * kF + f]);
      acc[gg] = fmaf(b4.x, w4.x, acc[gg]);
      acc[gg] = fmaf(b4.y, w4.y, acc[gg]);
      acc[gg] = fmaf(b4.z, w4.z, acc[gg]);
      acc[gg] = fmaf(b4.w, w4.w, acc[gg]);
    }
  }
#pragma unroll
  for (int gg = 0; gg < kG; ++gg) gi0T[(size_t)gg * T + t] = acc[gg];  // coalesced over t
}

// ---------------- Kernel B: sequential recurrence (R9 math, pipelined I/O).
// One float4 gi0 load per lane per 4 steps (prefetch distance 2 groups);
// one float4 top-state store per 4 steps to transposed topT[a][t].
__global__ __launch_bounds__(64)
__attribute__((amdgpu_waves_per_eu(1, 1)))
void seq_kernel(
    const float* __restrict__ Whh0, const float* __restrict__ bhh0,
    const float* __restrict__ Wih, const float* __restrict__ Whh,
    const float* __restrict__ bih, const float* __restrict__ bhh,
    const float* __restrict__ aW, const float* __restrict__ ab,
    const float* __restrict__ av, const float* __restrict__ avb,
    const float* __restrict__ gi0T, float* __restrict__ topT, int T) {
  const int lane = threadIdx.x & 63;
  const int grp = lane >> 4;
  const int a = lane & 15;
  const int gr = (grp == 0) ? a : (grp == 2 ? 32 + a : 16 + a);

  // --- per-lane PRE-ROTATED weight rows (R9 layout) ---
  float Wh[kL][kH];
  float Ux[3][kH];
  float aWj[kH];
#pragma unroll
  for (int j = 0; j < kH; ++j) {
    const int idx = (a - j) & 15;
    Wh[0][j] = Whh0[gr * kH + idx];
#pragma unroll
    for (int l = 1; l < kL; ++l) {
      Wh[l][j] = Whh[((l - 1) * kG + gr) * kH + idx];
      Ux[l - 1][j] = Wih[((l - 1) * kG + gr) * kH + idx];
    }
    aWj[j] = aW[(grp * kH + idx) * kA + a];
  }
  float bh[kL], bi[3];
  bh[0] = bhh0[gr];
#pragma unroll
  for (int l = 1; l < kL; ++l) {
    bh[l] = bhh[(l - 1) * kG + gr];
    bi[l - 1] = bih[(l - 1) * kG + gr];
  }
  float abr = ab[grp * kA + a];
  float avr = av[grp * kA + a];
  float avbr = avb[grp];

#pragma unroll
  for (int l = 0; l < kL; ++l) {
#pragma unroll
    for (int k = 0; k < kH; ++k) PIN(Wh[l][k]);
    PIN(bh[l]);
  }
#pragma unroll
  for (int l = 0; l < 3; ++l) {
#pragma unroll
    for (int k = 0; k < kH; ++k) PIN(Ux[l][k]);
    PIN(bi[l]);
  }
#pragma unroll
  for (int k = 0; k < kH; ++k) PIN(aWj[k]);
  PIN(abr); PIN(avr); PIN(avbr);

  float hs = 0.0f;  // packed state: lane 16*l+a holds h[l][a]

  const float* pG = gi0T + (size_t)gr * T;   // per-lane contiguous stream
  float* pT = topT + (size_t)a * T;          // lanes 48..63 store here

  const int NG = T / 4;  // groups of 4 steps
  float4 c4 = *reinterpret_cast<const float4*>(pG + 0);
  float4 n4 = *reinterpret_cast<const float4*>(pG + 4);

  // one full step; gcur = this step's gi0 value for this lane's gate-row
#define STEP(gcur, tslot)                                                     \
  {                                                                           \
    float hq[kL];                                                             \
    hq[0] = swap_sum16(swap_sum32(grp == 0 ? hs : 0.0f));                     \
    hq[1] = swap_sum32(swap_sum16(grp == 1 ? hs : 0.0f));                     \
    hq[2] = swap_sum16(swap_sum32(grp == 2 ? hs : 0.0f));                     \
    hq[3] = swap_sum32(swap_sum16(grp == 3 ? hs : 0.0f));                     \
    float xg[kL];                                                             \
    float sc[kL];                                                             \
    _Pragma("unroll")                                                         \
    for (int l = 0; l < kL; ++l) {                                            \
      const float accH = dot16r(Wh[l], hq[l], bh[l]);                         \
      const float accX = (l == 0) ? (gcur)                                    \
                                  : dot16r(Ux[l - 1], xg[l - 1], bi[l - 1]);  \
      const float sg = sigm(accX + accH);                                     \
      const float rv = swap_sum32(grp == 0 ? sg : 0.0f);                      \
      const float zv = swap_sum16(grp == 3 ? sg : 0.0f);                      \
      const float nt = tanh_f(fmaf(rv, accH, accX));                          \
      const float hnew = fmaf(zv, hq[l] - nt, nt);                            \
      xg[l] = swap_sum16(swap_sum32(grp == 2 ? hnew : 0.0f));                 \
      const float d = tanh_f(dot16r(aWj, xg[l], abr));                        \
      sc[l] = row_sum16(d * avr) + avbr;                                      \
    }                                                                         \
    const float s0 = (grp == 0) ? sc[0] : -1e30f;                             \
    const float s1 = (grp <= 1) ? sc[1] : -1e30f;                             \
    const float s2 = (grp <= 2) ? sc[2] : -1e30f;                             \
    const float s3 = sc[3];                                                   \
    const float m = fmaxf(fmaxf(s0, s1), fmaxf(s2, s3));                      \
    const float e0 = __builtin_amdgcn_exp2f((s0 - m) * kL2E);                 \
    const float e1 = __builtin_amdgcn_exp2f((s1 - m) * kL2E);                 \
    const float e2 = __builtin_amdgcn_exp2f((s2 - m) * kL2E);                 \
    const float e3 = __builtin_amdgcn_exp2f((s3 - m) * kL2E);                 \
    const float rden = fast_rcp((e0 + e1) + (e2 + e3));                       \
    float num = e0 * xg[0];                                                   \
    num = fmaf(e1, xg[1], num);                                               \
    num = fmaf(e2, xg[2], num);                                               \
    num = fmaf(e3, xg[3], num);                                               \
    hs = num * rden;                                                          \
    tslot = hs;                                                               \
  }

  for (int g = 0; g < NG; ++g) {
    const int gn = (g + 2 < NG) ? g + 2 : NG - 1;
    const float4 t4 = *reinterpret_cast<const float4*>(pG + (size_t)gn * 4);
    float o0, o1, o2, o3;
    STEP(c4.x, o0)
    STEP(c4.y, o1)
    STEP(c4.z, o2)
    STEP(c4.w, o3)
    if (lane >= 48) {
      *reinterpret_cast<float4*>(pT + (size_t)g * 4) = make_float4(o0, o1, o2, o3);
    }
    c4 = n4;
    n4 = t4;
  }
#undef STEP
}

// ---------------- Kernel C: out[t] = fc2( relu( fc1( topT[:,t] ) ) )
__global__ __launch_bounds__(256) void head_kernel(
    const float* __restrict__ topT, const float* __restrict__ fc1W,
    const float* __restrict__ fc1b, const float* __restrict__ fc2W,
    const float* __restrict__ fc2b, float* __restrict__ out, int T) {
  __shared__ __align__(16) float w1[32 * kH];
  __shared__ float b1[32], w2[32];
  for (int i = threadIdx.x; i < 32 * kH; i += blockDim.x) w1[i] = fc1W[i];
  if (threadIdx.x < 32) {
    b1[threadIdx.x] = fc1b[threadIdx.x];
    w2[threadIdx.x] = fc2W[threadIdx.x];
  }
  __syncthreads();
  int t = blockIdx.x * blockDim.x + threadIdx.x;
  if (t >= T) return;
  float hv[kH];
#pragma unroll
  for (int k = 0; k < kH; ++k) hv[k] = topT[(size_t)k * T + t];  // coalesced over t
  float o = fc2b[0];
#pragma unroll
  for (int mth = 0; mth < 32; ++mth) {
    float acc = b1[mth];
#pragma unroll
    for (int k = 0; k < kH; ++k) acc = fmaf(hv[k], w1[mth * kH + k], acc);
    acc = fmaxf(acc, 0.0f);
    o = fmaf(acc, w2[mth], o);
  }
  out[t] = o;
}

extern "C" void kernel_launch(void* const* d_in, const int* in_sizes, int n_in,
                              void* d_out, int out_size, void* d_ws, size_t ws_size,
                              hipStream_t stream) {
  const float* batch = (const float*)d_in[0];
  const float* Wih0  = (const float*)d_in[1];
  const float* Whh0  = (const float*)d_in[2];
  const float* bih0  = (const float*)d_in[3];
  const float* bhh0  = (const float*)d_in[4];
  const float* Wih   = (const float*)d_in[5];
  const float* Whh   = (const float*)d_in[6];
  const float* bih   = (const float*)d_in[7];
  const float* bhh   = (const float*)d_in[8];
  const float* aW    = (const float*)d_in[9];
  const float* ab    = (const float*)d_in[10];
  const float* av    = (const float*)d_in[11];
  const float* avb   = (const float*)d_in[12];
  const float* fc1W  = (const float*)d_in[13];
  const float* fc1b  = (const float*)d_in[14];
  const float* fc2W  = (const float*)d_in[15];
  const float* fc2b  = (const float*)d_in[16];
  float* out = (float*)d_out;

  const int T = in_sizes[0] / kF;  // 131072

  // workspace layout: gi0T [48][T] f32 | topT [16][T] f32
  float* gi0T = (float*)d_ws;
  float* topT = gi0T + (size_t)kG * T;

  const int blocks = (T + 255) / 256;
  gi0_kernel<<<blocks, 256, 0, stream>>>(batch, Wih0, bih0, gi0T, T);
  seq_kernel<<<1, 64, 0, stream>>>(Whh0, bhh0, Wih, Whh, bih, bhh,
                                   aW, ab, av, avb, gi0T, topT, T);
  head_kernel<<<blocks, 256, 0, stream>>>(topT, fc1W, fc1b, fc2W, fc2b, out, T);
}